// Round 1
// baseline (142.385 us; speedup 1.0000x reference)
//
#include <hip/hip_runtime.h>
#include <cstdint>
#include <cstddef>

typedef unsigned short u16;
typedef __attribute__((ext_vector_type(8))) short short8;
typedef __attribute__((ext_vector_type(4))) float f32x4;

#define CIN   512
#define COUT  512
#define BATCH 16
#define HWSZ  1024      // 32*32
#define PADW  34        // 32 + 2 halo

static constexpr float MOD_SCALE  = 0.044194173824159216f;   // 1/sqrt(512)
static constexpr float CONV_SCALE = 0.014731391274719739f;   // 1/sqrt(512*9)

// workspace layout (bytes)
#define WS_S    0                              // 8192 f32   (32 KB)
#define WS_DSC  (32*1024)                      // 8192 f32   (32 KB)
#define WS_WSQ  (64*1024)                      // 262144 f32 (1 MB)
#define WS_WBT  (64*1024 + 1024*1024)          // 9*512*512 bf16 (4.5 MB)
#define WS_XSP  (WS_WBT + 9*512*512*2)         // 16*34*34*512 bf16 (~18 MB)

__device__ __forceinline__ u16 f2bf(float f) {
  union { float f; uint32_t u; } v; v.f = f;
  uint32_t r = v.u + 0x7fffu + ((v.u >> 16) & 1u);   // RNE
  return (u16)(r >> 16);
}

__device__ __forceinline__ void gload16(const void* g, void* l) {
  __builtin_amdgcn_global_load_lds(
      (const __attribute__((address_space(1))) void*)g,
      (__attribute__((address_space(3))) void*)l, 16, 0, 0);
}

// ---------------- s[b,i] = mod_scale * style[b,:] . mod_w[i,:] + mod_b[i] ----------------
// one wave per (b,i); 8192 waves
__global__ void k_style(const float* __restrict__ style, const float* __restrict__ mod_w,
                        const float* __restrict__ mod_b, float* __restrict__ s_out) {
  int gid  = blockIdx.x * blockDim.x + threadIdx.x;
  int w    = gid >> 6, lane = gid & 63;
  int b    = w >> 9, i = w & 511;
  const float4* st = (const float4*)(style + (size_t)b * 512);
  const float4* mw = (const float4*)(mod_w + (size_t)i * 512);
  float4 a0 = st[lane * 2], a1 = st[lane * 2 + 1];
  float4 w0 = mw[lane * 2], w1 = mw[lane * 2 + 1];
  float acc = a0.x*w0.x + a0.y*w0.y + a0.z*w0.z + a0.w*w0.w
            + a1.x*w1.x + a1.y*w1.y + a1.z*w1.z + a1.w*w1.w;
  #pragma unroll
  for (int off = 32; off; off >>= 1) acc += __shfl_xor(acc, off);
  if (lane == 0) s_out[w] = acc * MOD_SCALE + mod_b[i];
}

// ---------------- wsq[o,i] = sum_k weight[o,i,k]^2 ----------------
__global__ void k_wsq(const float* __restrict__ w, float* __restrict__ wsq) {
  int idx = blockIdx.x * 256 + threadIdx.x;          // 262144
  const float* p = w + (size_t)idx * 9;
  float a = 0.f;
  #pragma unroll
  for (int j = 0; j < 9; ++j) a += p[j] * p[j];
  wsq[idx] = a;
}

// ---------------- dscale[b,o] = conv_scale * rsqrt(cs^2 * sum_i wsq[o,i]*s[b,i]^2 + 1e-8) ----
__global__ void k_dscale(const float* __restrict__ wsq, const float* __restrict__ s,
                         float* __restrict__ dsc) {
  int gid  = blockIdx.x * blockDim.x + threadIdx.x;
  int w    = gid >> 6, lane = gid & 63;
  int b    = w >> 9, o = w & 511;
  const float4* q4 = (const float4*)(wsq + (size_t)o * 512);
  const float4* s4 = (const float4*)(s   + (size_t)b * 512);
  float4 q0 = q4[lane * 2], q1 = q4[lane * 2 + 1];
  float4 t0 = s4[lane * 2], t1 = s4[lane * 2 + 1];
  float acc = q0.x*t0.x*t0.x + q0.y*t0.y*t0.y + q0.z*t0.z*t0.z + q0.w*t0.w*t0.w
            + q1.x*t1.x*t1.x + q1.y*t1.y*t1.y + q1.z*t1.z*t1.z + q1.w*t1.w*t1.w;
  #pragma unroll
  for (int off = 32; off; off >>= 1) acc += __shfl_xor(acc, off);
  if (lane == 0)
    dsc[w] = CONV_SCALE * rsqrtf(acc * CONV_SCALE * CONV_SCALE + 1e-8f);
}

// ---------------- wbT[kxy][o][i] = bf16(weight[o][i][kxy]) ----------------
__global__ void k_wbt(const float* __restrict__ w, u16* __restrict__ wbt) {
  int idx = blockIdx.x * 256 + threadIdx.x;          // 262144 = o*512+i
  const float* p = w + (size_t)idx * 9;
  #pragma unroll
  for (int kxy = 0; kxy < 9; ++kxy)
    wbt[(size_t)kxy * 262144 + idx] = f2bf(p[kxy]);
}

// ---------------- xs_p[b][y+1][x+1][i] = bf16(x[b][i][y][x] * s[b][i])  (NCHW->NHWC) --------
__global__ void k_xs(const float* __restrict__ x, const float* __restrict__ s,
                     u16* __restrict__ xsp) {
  __shared__ float tile[64][33];
  int icb = blockIdx.x, y = blockIdx.y, b = blockIdx.z;
  int t = threadIdx.x;
  int i0 = icb * 64;
  int c  = t & 31;       // x coord
  int r0 = t >> 5;       // 0..7
  #pragma unroll
  for (int it = 0; it < 8; ++it) {
    int row = r0 + it * 8;                           // i_loc 0..63
    float sv = s[b * 512 + i0 + row];
    tile[row][c] = x[((size_t)(b * 512 + i0 + row)) * 1024 + y * 32 + c] * sv;
  }
  __syncthreads();
  int il = t & 63;
  int x0 = t >> 6;       // 0..3
  #pragma unroll
  for (int it = 0; it < 8; ++it) {
    int xc = x0 + it * 4;
    xsp[((size_t)((b * PADW + y + 1) * PADW) + (xc + 1)) * 512 + i0 + il] = f2bf(tile[il][xc]);
  }
}

// ---------------- implicit-GEMM conv + fused epilogue ----------------
// D[o][m] tile 128x128, K = 9*512 in steps of 64, 4 waves (2x2 of 64x64)
__global__ __launch_bounds__(256) void k_conv(
    const u16* __restrict__ wbt, const u16* __restrict__ xsp,
    const float* __restrict__ dsc, const float* __restrict__ noise,
    const float* __restrict__ nw, const float* __restrict__ abias,
    float* __restrict__ out)
{
  __shared__ u16 Ald[128 * 64];   // [o_loc][k]  16 KB
  __shared__ u16 Bld[128 * 64];   // [m_loc][k]  16 KB

  const int tid  = threadIdx.x;
  const int wave = tid >> 6, lane = tid & 63;
  const int o0 = blockIdx.x * 128;
  const int m0 = blockIdx.y * 128;
  const int b  = m0 >> 10;        // uniform per block (128 | 1024)

  // per-lane staging bases (4 global_load_lds of 16B per wave per tile)
  const u16* gA[4]; const u16* gB[4]; u16* lA[4]; u16* lB[4];
  #pragma unroll
  for (int q = 0; q < 4; ++q) {
    int r  = wave * 32 + q * 8 + (lane >> 3);
    int cc = (lane & 7) * 8;
    gA[q] = wbt + (size_t)(o0 + r) * 512 + cc;
    int mg = m0 + r;
    int yy = (mg >> 5) & 31, xx = mg & 31;
    gB[q] = xsp + ((size_t)(b * PADW + yy) * PADW + xx) * 512 + cc;
    lA[q] = &Ald[(wave * 32 + q * 8) * 64];
    lB[q] = &Bld[(wave * 32 + q * 8) * 64];
  }

  f32x4 acc[4][4];
  #pragma unroll
  for (int i = 0; i < 4; ++i)
    #pragma unroll
    for (int j = 0; j < 4; ++j) acc[i][j] = (f32x4){0.f, 0.f, 0.f, 0.f};

  const int wo = (wave >> 1) * 64;   // o sub-block
  const int wm = (wave & 1) * 64;    // m sub-block
  const int lrow = lane & 15;
  const int lk   = (lane >> 4) * 8;

  for (int ks = 0; ks < 72; ++ks) {
    int kxy = ks >> 3;
    int ib  = (ks & 7) << 6;
    int ky  = kxy / 3, kx = kxy - ky * 3;
    int offA = kxy * 262144 + ib;
    int offB = ((ky * PADW + kx) << 9) + ib;

    __syncthreads();                 // previous compute done before overwrite
    #pragma unroll
    for (int q = 0; q < 4; ++q) gload16(gA[q] + offA, lA[q]);
    #pragma unroll
    for (int q = 0; q < 4; ++q) gload16(gB[q] + offB, lB[q]);
    asm volatile("s_waitcnt vmcnt(0)" ::: "memory");
    __syncthreads();                 // all waves' tiles visible

    #pragma unroll
    for (int kh = 0; kh < 2; ++kh) {
      int ko = kh * 32 + lk;
      short8 av[4], bv[4];
      #pragma unroll
      for (int mi = 0; mi < 4; ++mi)
        av[mi] = *(const short8*)&Ald[(wo + mi * 16 + lrow) * 64 + ko];
      #pragma unroll
      for (int ni = 0; ni < 4; ++ni)
        bv[ni] = *(const short8*)&Bld[(wm + ni * 16 + lrow) * 64 + ko];
      #pragma unroll
      for (int mi = 0; mi < 4; ++mi)
        #pragma unroll
        for (int ni = 0; ni < 4; ++ni)
          acc[mi][ni] = __builtin_amdgcn_mfma_f32_16x16x32_bf16(
              av[mi], bv[ni], acc[mi][ni], 0, 0, 0);
    }
  }

  // epilogue: demod*conv_scale, noise, bias, leaky(0.2)*sqrt(2)
  const float nwv = nw[0];
  const int mrow = (lane >> 4) << 2;
  #pragma unroll
  for (int mi = 0; mi < 4; ++mi) {
    #pragma unroll
    for (int ni = 0; ni < 4; ++ni) {
      int mg = m0 + wm + ni * 16 + lrow;
      int hw = mg & 1023;
      float nz = nwv * noise[b * 1024 + hw];
      #pragma unroll
      for (int r = 0; r < 4; ++r) {
        int og = o0 + wo + mi * 16 + mrow + r;
        float v = acc[mi][ni][r] * dsc[b * 512 + og] + nz + abias[og];
        v = (v > 0.f ? v : 0.2f * v) * 1.4142135623730951f;
        out[(size_t)(b * 512 + og) * 1024 + hw] = v;
      }
    }
  }
}

extern "C" void kernel_launch(void* const* d_in, const int* in_sizes, int n_in,
                              void* d_out, int out_size, void* d_ws, size_t ws_size,
                              hipStream_t stream) {
  const float* x      = (const float*)d_in[0];
  const float* style  = (const float*)d_in[1];
  const float* noise  = (const float*)d_in[2];
  const float* weight = (const float*)d_in[3];
  const float* mod_w  = (const float*)d_in[4];
  const float* mod_b  = (const float*)d_in[5];
  const float* nw     = (const float*)d_in[6];
  const float* abias  = (const float*)d_in[7];
  float* out = (float*)d_out;

  char* ws = (char*)d_ws;
  float* s_buf = (float*)(ws + WS_S);
  float* dsc   = (float*)(ws + WS_DSC);
  float* wsq   = (float*)(ws + WS_WSQ);
  u16*   wbt   = (u16*)(ws + WS_WBT);
  u16*   xsp   = (u16*)(ws + WS_XSP);

  // zero padded input (borders must be 0 every call; ws is not preserved)
  hipMemsetAsync(xsp, 0, (size_t)BATCH * PADW * PADW * 512 * 2, stream);

  k_style <<<2048, 256, 0, stream>>>(style, mod_w, mod_b, s_buf);
  k_wsq   <<<1024, 256, 0, stream>>>(weight, wsq);
  k_dscale<<<2048, 256, 0, stream>>>(wsq, s_buf, dsc);
  k_wbt   <<<1024, 256, 0, stream>>>(weight, wbt);
  k_xs    <<<dim3(8, 32, 16), 256, 0, stream>>>(x, s_buf, xsp);
  k_conv  <<<dim3(4, 128), 256, 0, stream>>>(wbt, xsp, dsc, noise, nw, abias, out);
}

// Round 2
// 126.606 us; speedup vs baseline: 1.1246x; 1.1246x over previous
//
#include <hip/hip_runtime.h>
#include <cstdint>
#include <cstddef>

typedef unsigned short u16;
typedef __attribute__((ext_vector_type(8))) short short8;
typedef __attribute__((ext_vector_type(4))) float f32x4;

#define CIN   512
#define COUT  512
#define BATCH 16
#define HWSZ  1024      // 32*32
#define PADW  34        // 32 + 2 halo

static constexpr float MOD_SCALE  = 0.044194173824159216f;   // 1/sqrt(512)
static constexpr float CONV_SCALE = 0.014731391274719739f;   // 1/sqrt(512*9)

// workspace layout (bytes)
#define WS_S    0                              // 8192 f32   (32 KB)
#define WS_DSC  (32*1024)                      // 8192 f32   (32 KB)
#define WS_WSQ  (64*1024)                      // 262144 f32 (1 MB)
#define WS_WBT  (64*1024 + 1024*1024)          // 9*512*512 bf16 (4.5 MB)
#define WS_XSP  (WS_WBT + 9*512*512*2)         // 16*34*34*512 bf16 (~18 MB)

__device__ __forceinline__ u16 f2bf(float f) {
  union { float f; uint32_t u; } v; v.f = f;
  uint32_t r = v.u + 0x7fffu + ((v.u >> 16) & 1u);   // RNE
  return (u16)(r >> 16);
}

__device__ __forceinline__ void gload16(const void* g, void* l) {
  __builtin_amdgcn_global_load_lds(
      (const __attribute__((address_space(1))) void*)g,
      (__attribute__((address_space(3))) void*)l, 16, 0, 0);
}

// ---------------- s[b,i] = mod_scale * style[b,:] . mod_w[i,:] + mod_b[i] ----------------
__global__ void k_style(const float* __restrict__ style, const float* __restrict__ mod_w,
                        const float* __restrict__ mod_b, float* __restrict__ s_out) {
  int gid  = blockIdx.x * blockDim.x + threadIdx.x;
  int w    = gid >> 6, lane = gid & 63;
  int b    = w >> 9, i = w & 511;
  const float4* st = (const float4*)(style + (size_t)b * 512);
  const float4* mw = (const float4*)(mod_w + (size_t)i * 512);
  float4 a0 = st[lane * 2], a1 = st[lane * 2 + 1];
  float4 w0 = mw[lane * 2], w1 = mw[lane * 2 + 1];
  float acc = a0.x*w0.x + a0.y*w0.y + a0.z*w0.z + a0.w*w0.w
            + a1.x*w1.x + a1.y*w1.y + a1.z*w1.z + a1.w*w1.w;
  #pragma unroll
  for (int off = 32; off; off >>= 1) acc += __shfl_xor(acc, off);
  if (lane == 0) s_out[w] = acc * MOD_SCALE + mod_b[i];
}

// ---------------- fused: wsq[o,i] = sum_k w^2 ; wbT[kxy][o][i] = bf16(w) ----------------
__global__ void k_wprep(const float* __restrict__ w, float* __restrict__ wsq,
                        u16* __restrict__ wbt) {
  int idx = blockIdx.x * 256 + threadIdx.x;          // 262144 = o*512+i
  const float* p = w + (size_t)idx * 9;
  float a = 0.f;
  #pragma unroll
  for (int kxy = 0; kxy < 9; ++kxy) {
    float v = p[kxy];
    a += v * v;
    wbt[(size_t)kxy * 262144 + idx] = f2bf(v);
  }
  wsq[idx] = a;
}

// ---------------- dscale[b,o] = conv_scale * rsqrt(cs^2 * sum_i wsq[o,i]*s[b,i]^2 + 1e-8) ----
__global__ void k_dscale(const float* __restrict__ wsq, const float* __restrict__ s,
                         float* __restrict__ dsc) {
  int gid  = blockIdx.x * blockDim.x + threadIdx.x;
  int w    = gid >> 6, lane = gid & 63;
  int b    = w >> 9, o = w & 511;
  const float4* q4 = (const float4*)(wsq + (size_t)o * 512);
  const float4* s4 = (const float4*)(s   + (size_t)b * 512);
  float4 q0 = q4[lane * 2], q1 = q4[lane * 2 + 1];
  float4 t0 = s4[lane * 2], t1 = s4[lane * 2 + 1];
  float acc = q0.x*t0.x*t0.x + q0.y*t0.y*t0.y + q0.z*t0.z*t0.z + q0.w*t0.w*t0.w
            + q1.x*t1.x*t1.x + q1.y*t1.y*t1.y + q1.z*t1.z*t1.z + q1.w*t1.w*t1.w;
  #pragma unroll
  for (int off = 32; off; off >>= 1) acc += __shfl_xor(acc, off);
  if (lane == 0)
    dsc[w] = CONV_SCALE * rsqrtf(acc * CONV_SCALE * CONV_SCALE + 1e-8f);
}

// ---------------- xs_p[b][y+1][x+1][i] = bf16(x[b][i][y][x] * s[b][i])  (NCHW->NHWC) --------
__global__ void k_xs(const float* __restrict__ x, const float* __restrict__ s,
                     u16* __restrict__ xsp) {
  __shared__ float tile[64][33];
  int icb = blockIdx.x, y = blockIdx.y, b = blockIdx.z;
  int t = threadIdx.x;
  int i0 = icb * 64;
  int c  = t & 31;       // x coord
  int r0 = t >> 5;       // 0..7
  #pragma unroll
  for (int it = 0; it < 8; ++it) {
    int row = r0 + it * 8;                           // i_loc 0..63
    float sv = s[b * 512 + i0 + row];
    tile[row][c] = x[((size_t)(b * 512 + i0 + row)) * 1024 + y * 32 + c] * sv;
  }
  __syncthreads();
  int il = t & 63;
  int x0 = t >> 6;       // 0..3
  #pragma unroll
  for (int it = 0; it < 8; ++it) {
    int xc = x0 + it * 4;
    xsp[((size_t)((b * PADW + y + 1) * PADW) + (xc + 1)) * 512 + i0 + il] = f2bf(tile[il][xc]);
  }
}

// ---------------- implicit-GEMM conv + fused epilogue ----------------
// D[o][m] tile 128x128, K = 9*512 in steps of 64, 4 waves (2x2 of 64x64)
// LDS tiles XOR-swizzled (T2): 16-B chunk index ^= (row & 7); swizzle applied on
// the GLOBAL source (global_load_lds writes linearly) and on the ds_read address.
__global__ __launch_bounds__(256) void k_conv(
    const u16* __restrict__ wbt, const u16* __restrict__ xsp,
    const float* __restrict__ dsc, const float* __restrict__ noise,
    const float* __restrict__ nw, const float* __restrict__ abias,
    float* __restrict__ out)
{
  __shared__ u16 Ald[128 * 64];   // [o_loc][k]  16 KB (swizzled)
  __shared__ u16 Bld[128 * 64];   // [m_loc][k]  16 KB (swizzled)

  const int tid  = threadIdx.x;
  const int wave = tid >> 6, lane = tid & 63;
  const int o0 = blockIdx.x * 128;
  const int m0 = blockIdx.y * 128;
  const int b  = m0 >> 10;        // uniform per block (128 | 1024)

  // per-lane staging bases: lane covers row (base + lane>>3), 16-B chunk (lane&7).
  // swizzled source chunk = (lane&7) ^ (row&7) = (lane&7) ^ (lane>>3)
  const u16* gA[4]; const u16* gB[4]; u16* lA[4]; u16* lB[4];
  const int cc = (((lane & 7) ^ (lane >> 3)) * 8);
  #pragma unroll
  for (int q = 0; q < 4; ++q) {
    int r  = wave * 32 + q * 8 + (lane >> 3);
    gA[q] = wbt + (size_t)(o0 + r) * 512 + cc;
    int mg = m0 + r;
    int yy = (mg >> 5) & 31, xx = mg & 31;
    gB[q] = xsp + ((size_t)(b * PADW + yy) * PADW + xx) * 512 + cc;
    lA[q] = &Ald[(wave * 32 + q * 8) * 64];
    lB[q] = &Bld[(wave * 32 + q * 8) * 64];
  }

  f32x4 acc[4][4];
  #pragma unroll
  for (int i = 0; i < 4; ++i)
    #pragma unroll
    for (int j = 0; j < 4; ++j) acc[i][j] = (f32x4){0.f, 0.f, 0.f, 0.f};

  const int wo = (wave >> 1) * 64;   // o sub-block
  const int wm = (wave & 1) * 64;    // m sub-block
  const int lrow = lane & 15;
  const int lk   = (lane >> 4) * 8;
  const int rsw  = (lrow & 7) << 3;  // read-side swizzle (u16 units)

  for (int ks = 0; ks < 72; ++ks) {
    int kxy = ks >> 3;
    int ib  = (ks & 7) << 6;
    int ky  = kxy / 3, kx = kxy - ky * 3;
    int offA = kxy * 262144 + ib;
    int offB = ((ky * PADW + kx) << 9) + ib;

    __syncthreads();                 // previous compute done before overwrite
    #pragma unroll
    for (int q = 0; q < 4; ++q) gload16(gA[q] + offA, lA[q]);
    #pragma unroll
    for (int q = 0; q < 4; ++q) gload16(gB[q] + offB, lB[q]);
    asm volatile("s_waitcnt vmcnt(0)" ::: "memory");
    __syncthreads();                 // all waves' tiles visible

    #pragma unroll
    for (int kh = 0; kh < 2; ++kh) {
      int kos = (kh * 32 + lk) ^ rsw;
      short8 av[4], bv[4];
      #pragma unroll
      for (int mi = 0; mi < 4; ++mi)
        av[mi] = *(const short8*)&Ald[(wo + mi * 16 + lrow) * 64 + kos];
      #pragma unroll
      for (int ni = 0; ni < 4; ++ni)
        bv[ni] = *(const short8*)&Bld[(wm + ni * 16 + lrow) * 64 + kos];
      #pragma unroll
      for (int mi = 0; mi < 4; ++mi)
        #pragma unroll
        for (int ni = 0; ni < 4; ++ni)
          acc[mi][ni] = __builtin_amdgcn_mfma_f32_16x16x32_bf16(
              av[mi], bv[ni], acc[mi][ni], 0, 0, 0);
    }
  }

  // epilogue: demod*conv_scale, noise, bias, leaky(0.2)*sqrt(2)
  const float nwv = nw[0];
  const int mrow = (lane >> 4) << 2;
  #pragma unroll
  for (int mi = 0; mi < 4; ++mi) {
    #pragma unroll
    for (int ni = 0; ni < 4; ++ni) {
      int mg = m0 + wm + ni * 16 + lrow;
      int hw = mg & 1023;
      float nz = nwv * noise[b * 1024 + hw];
      #pragma unroll
      for (int r = 0; r < 4; ++r) {
        int og = o0 + wo + mi * 16 + mrow + r;
        float v = acc[mi][ni][r] * dsc[b * 512 + og] + nz + abias[og];
        v = (v > 0.f ? v : 0.2f * v) * 1.4142135623730951f;
        out[(size_t)(b * 512 + og) * 1024 + hw] = v;
      }
    }
  }
}

extern "C" void kernel_launch(void* const* d_in, const int* in_sizes, int n_in,
                              void* d_out, int out_size, void* d_ws, size_t ws_size,
                              hipStream_t stream) {
  const float* x      = (const float*)d_in[0];
  const float* style  = (const float*)d_in[1];
  const float* noise  = (const float*)d_in[2];
  const float* weight = (const float*)d_in[3];
  const float* mod_w  = (const float*)d_in[4];
  const float* mod_b  = (const float*)d_in[5];
  const float* nw     = (const float*)d_in[6];
  const float* abias  = (const float*)d_in[7];
  float* out = (float*)d_out;

  char* ws = (char*)d_ws;
  float* s_buf = (float*)(ws + WS_S);
  float* dsc   = (float*)(ws + WS_DSC);
  float* wsq   = (float*)(ws + WS_WSQ);
  u16*   wbt   = (u16*)(ws + WS_WBT);
  u16*   xsp   = (u16*)(ws + WS_XSP);

  // zero padded input (borders must be 0 every call; ws is not preserved)
  hipMemsetAsync(xsp, 0, (size_t)BATCH * PADW * PADW * 512 * 2, stream);

  k_style <<<2048, 256, 0, stream>>>(style, mod_w, mod_b, s_buf);
  k_wprep <<<1024, 256, 0, stream>>>(weight, wsq, wbt);
  k_dscale<<<2048, 256, 0, stream>>>(wsq, s_buf, dsc);
  k_xs    <<<dim3(8, 32, 16), 256, 0, stream>>>(x, s_buf, xsp);
  k_conv  <<<dim3(4, 128), 256, 0, stream>>>(wbt, xsp, dsc, noise, nw, abias, out);
}